// Round 1
// baseline (358.844 us; speedup 1.0000x reference)
//
#include <hip/hip_runtime.h>
#include <hip/hip_bf16.h>

// Phase 1: values[i] = pred[i] * (ub[i] - lb[i]) + lb[i]
__global__ void denorm_kernel(const float* __restrict__ pred,
                              const float* __restrict__ lb,
                              const float* __restrict__ ub,
                              float* __restrict__ values, int n) {
    int i = blockIdx.x * blockDim.x + threadIdx.x;
    if (i < n) {
        values[i] = pred[i] * (ub[i] - lb[i]) + lb[i];
    }
}

// Phase 2: segmented scatter-add. constr_idx is sorted, so do a wave-level
// head-segmented inclusive scan and emit one atomicAdd per (segment, wave).
__global__ void scatter_kernel(const float* __restrict__ coeff,
                               const int* __restrict__ constr_idx,
                               const int* __restrict__ var_idx,
                               const float* __restrict__ values,
                               float* __restrict__ ax, int nnz) {
    int i = blockIdx.x * blockDim.x + threadIdx.x;
    int lane = threadIdx.x & 63;

    int seg = -1;
    float v = 0.0f;
    if (i < nnz) {
        seg = constr_idx[i];
        v = coeff[i] * values[var_idx[i]];
    }

    // Head-segmented inclusive scan across the 64-lane wave.
    #pragma unroll
    for (int off = 1; off < 64; off <<= 1) {
        float ov = __shfl_up(v, off, 64);
        int   os = __shfl_up(seg, off, 64);
        if (lane >= off && os == seg) v += ov;
    }

    // Tail of each segment within the wave writes the partial.
    int nseg = __shfl_down(seg, 1, 64);
    bool is_tail = (lane == 63) || (nseg != seg);
    if (is_tail && seg >= 0) {
        atomicAdd(&ax[seg], v);
    }
}

// Phase 3: violations by sense, block reduction, one atomic per block.
__global__ void violation_kernel(const float* __restrict__ ax,
                                 const float* __restrict__ rhs,
                                 const int* __restrict__ sense,
                                 float* __restrict__ out,
                                 int n, float inv_n) {
    __shared__ float warp_sums[4];  // 256 threads = 4 waves
    int i = blockIdx.x * blockDim.x + threadIdx.x;

    float viol = 0.0f;
    if (i < n) {
        float diff = ax[i] - rhs[i];
        int s = sense[i];
        if (s == 1)      viol = fmaxf(diff, 0.0f);
        else if (s == 2) viol = fmaxf(-diff, 0.0f);
        else if (s == 3) viol = fabsf(diff);
    }

    // Wave reduce (64 lanes).
    #pragma unroll
    for (int off = 32; off > 0; off >>= 1) {
        viol += __shfl_down(viol, off, 64);
    }
    int lane = threadIdx.x & 63;
    int wave = threadIdx.x >> 6;
    if (lane == 0) warp_sums[wave] = viol;
    __syncthreads();

    if (threadIdx.x == 0) {
        float s = warp_sums[0] + warp_sums[1] + warp_sums[2] + warp_sums[3];
        atomicAdd(out, s * inv_n);
    }
}

extern "C" void kernel_launch(void* const* d_in, const int* in_sizes, int n_in,
                              void* d_out, int out_size, void* d_ws, size_t ws_size,
                              hipStream_t stream) {
    const float* pred       = (const float*)d_in[0];
    const float* coeff      = (const float*)d_in[1];
    const float* rhs        = (const float*)d_in[2];
    const float* lb         = (const float*)d_in[3];
    const float* ub         = (const float*)d_in[4];
    const int*   constr_idx = (const int*)d_in[5];
    const int*   var_idx    = (const int*)d_in[6];
    const int*   sense      = (const int*)d_in[7];

    const int n_vars    = in_sizes[0];
    const int nnz       = in_sizes[1];
    const int n_constrs = in_sizes[2];

    float* values = (float*)d_ws;                 // n_vars floats
    float* ax     = values + n_vars;              // n_constrs floats
    float* out    = (float*)d_out;

    // Workspace/output are poisoned 0xAA before each timed call: zero what we
    // accumulate into. (hipMemsetAsync is stream-ordered & graph-capturable.)
    hipMemsetAsync(ax, 0, (size_t)n_constrs * sizeof(float), stream);
    hipMemsetAsync(out, 0, sizeof(float), stream);

    const int BLK = 256;
    denorm_kernel<<<(n_vars + BLK - 1) / BLK, BLK, 0, stream>>>(
        pred, lb, ub, values, n_vars);
    scatter_kernel<<<(nnz + BLK - 1) / BLK, BLK, 0, stream>>>(
        coeff, constr_idx, var_idx, values, ax, nnz);
    violation_kernel<<<(n_constrs + BLK - 1) / BLK, BLK, 0, stream>>>(
        ax, rhs, sense, out, n_constrs, 1.0f / (float)n_constrs);
}

// Round 3
// 319.969 us; speedup vs baseline: 1.1215x; 1.1215x over previous
//
#include <hip/hip_runtime.h>
#include <hip/hip_bf16.h>

// Clang-native vector types (HIP_vector_type is rejected by
// __builtin_nontemporal_load).
typedef float vfloat4 __attribute__((ext_vector_type(4)));
typedef int   vint4   __attribute__((ext_vector_type(4)));

// Phase 1 (fused): values = pred*(ub-lb)+lb, zero ax, zero out.
__global__ void denorm_zero_kernel(const vfloat4* __restrict__ pred,
                                   const vfloat4* __restrict__ lb,
                                   const vfloat4* __restrict__ ub,
                                   vfloat4* __restrict__ values,
                                   vfloat4* __restrict__ ax,
                                   float* __restrict__ out,
                                   int n4v, int n4c) {
    int i = blockIdx.x * blockDim.x + threadIdx.x;
    if (i < n4v) {
        vfloat4 p = pred[i], l = lb[i], u = ub[i];
        vfloat4 v;
        v.x = fmaf(p.x, u.x - l.x, l.x);
        v.y = fmaf(p.y, u.y - l.y, l.y);
        v.z = fmaf(p.z, u.z - l.z, l.z);
        v.w = fmaf(p.w, u.w - l.w, l.w);
        values[i] = v;
    }
    if (i < n4c) {
        vfloat4 z = {0.f, 0.f, 0.f, 0.f};
        ax[i] = z;
    }
    if (i == 0) *out = 0.0f;
}

// Phase 2: thread-coarsened segmented scatter-add. constr_idx is sorted;
// each thread takes K=16 consecutive nnz (avg segment length = 16), does a
// serial segmented sum in registers, one atomicAdd per segment run.
// Streaming arrays use nontemporal loads to keep the values table L2-resident.
__global__ void scatter_kernel(const vfloat4* __restrict__ coeff,
                               const vint4* __restrict__ cidx,
                               const vint4* __restrict__ vidx,
                               const float* __restrict__ values,
                               float* __restrict__ ax,
                               int nnz) {
    const int K = 16;
    int t = blockIdx.x * blockDim.x + threadIdx.x;
    long base = (long)t * K;
    if (base >= nnz) return;

    if (base + K <= nnz) {
        // Fast path: full chunk, 16B x4 loads.
        long b4 = (long)t * 4;
        int cseg[16]; int vix[16]; float cf[16];
        #pragma unroll
        for (int j = 0; j < 4; j++) {
            vint4 c = __builtin_nontemporal_load(&cidx[b4 + j]);
            cseg[4*j+0] = c.x; cseg[4*j+1] = c.y; cseg[4*j+2] = c.z; cseg[4*j+3] = c.w;
        }
        #pragma unroll
        for (int j = 0; j < 4; j++) {
            vint4 v = __builtin_nontemporal_load(&vidx[b4 + j]);
            vix[4*j+0] = v.x; vix[4*j+1] = v.y; vix[4*j+2] = v.z; vix[4*j+3] = v.w;
        }
        float vals[16];
        #pragma unroll
        for (int k = 0; k < 16; k++) vals[k] = values[vix[k]];
        #pragma unroll
        for (int j = 0; j < 4; j++) {
            vfloat4 f = __builtin_nontemporal_load(&coeff[b4 + j]);
            cf[4*j+0] = f.x; cf[4*j+1] = f.y; cf[4*j+2] = f.z; cf[4*j+3] = f.w;
        }

        int cur = cseg[0];
        float acc = cf[0] * vals[0];
        #pragma unroll
        for (int k = 1; k < 16; k++) {
            if (cseg[k] == cur) {
                acc = fmaf(cf[k], vals[k], acc);
            } else {
                atomicAdd(&ax[cur], acc);
                cur = cseg[k];
                acc = cf[k] * vals[k];
            }
        }
        atomicAdd(&ax[cur], acc);
    } else {
        // Tail chunk: scalar.
        const int* ci = (const int*)cidx;
        const int* vi = (const int*)vidx;
        const float* cf = (const float*)coeff;
        int cur = ci[base];
        float acc = cf[base] * values[vi[base]];
        for (long k = base + 1; k < nnz; k++) {
            int s = ci[k];
            float p = cf[k] * values[vi[k]];
            if (s == cur) acc += p;
            else { atomicAdd(&ax[cur], acc); cur = s; acc = p; }
        }
        atomicAdd(&ax[cur], acc);
    }
}

// Phase 3: violations by sense (x4 vectorized), block reduce, one atomic.
__global__ void violation_kernel(const vfloat4* __restrict__ ax,
                                 const vfloat4* __restrict__ rhs,
                                 const vint4* __restrict__ sense,
                                 float* __restrict__ out,
                                 int n4, float inv_n) {
    __shared__ float warp_sums[4];  // 256 threads = 4 waves
    int i = blockIdx.x * blockDim.x + threadIdx.x;

    float viol = 0.0f;
    if (i < n4) {
        vfloat4 a = ax[i], r = rhs[i];
        vint4 s = sense[i];
        float d, pos, neg;
        d = a.x - r.x; pos = fmaxf(d, 0.f); neg = fmaxf(-d, 0.f);
        viol += (s.x == 1) ? pos : (s.x == 2) ? neg : (s.x == 3) ? (pos + neg) : 0.f;
        d = a.y - r.y; pos = fmaxf(d, 0.f); neg = fmaxf(-d, 0.f);
        viol += (s.y == 1) ? pos : (s.y == 2) ? neg : (s.y == 3) ? (pos + neg) : 0.f;
        d = a.z - r.z; pos = fmaxf(d, 0.f); neg = fmaxf(-d, 0.f);
        viol += (s.z == 1) ? pos : (s.z == 2) ? neg : (s.z == 3) ? (pos + neg) : 0.f;
        d = a.w - r.w; pos = fmaxf(d, 0.f); neg = fmaxf(-d, 0.f);
        viol += (s.w == 1) ? pos : (s.w == 2) ? neg : (s.w == 3) ? (pos + neg) : 0.f;
    }

    #pragma unroll
    for (int off = 32; off > 0; off >>= 1) {
        viol += __shfl_down(viol, off, 64);
    }
    int lane = threadIdx.x & 63;
    int wave = threadIdx.x >> 6;
    if (lane == 0) warp_sums[wave] = viol;
    __syncthreads();

    if (threadIdx.x == 0) {
        float s = warp_sums[0] + warp_sums[1] + warp_sums[2] + warp_sums[3];
        atomicAdd(out, s * inv_n);
    }
}

extern "C" void kernel_launch(void* const* d_in, const int* in_sizes, int n_in,
                              void* d_out, int out_size, void* d_ws, size_t ws_size,
                              hipStream_t stream) {
    const float* pred       = (const float*)d_in[0];
    const float* coeff      = (const float*)d_in[1];
    const float* rhs        = (const float*)d_in[2];
    const float* lb         = (const float*)d_in[3];
    const float* ub         = (const float*)d_in[4];
    const int*   constr_idx = (const int*)d_in[5];
    const int*   var_idx    = (const int*)d_in[6];
    const int*   sense      = (const int*)d_in[7];

    const int n_vars    = in_sizes[0];
    const int nnz       = in_sizes[1];
    const int n_constrs = in_sizes[2];

    float* values = (float*)d_ws;       // n_vars floats
    float* ax     = values + n_vars;    // n_constrs floats (16B-aligned: n_vars%4==0)
    float* out    = (float*)d_out;

    const int BLK = 256;

    int n4v = n_vars / 4, n4c = n_constrs / 4;
    int n4max = (n4v > n4c) ? n4v : n4c;
    denorm_zero_kernel<<<(n4max + BLK - 1) / BLK, BLK, 0, stream>>>(
        (const vfloat4*)pred, (const vfloat4*)lb, (const vfloat4*)ub,
        (vfloat4*)values, (vfloat4*)ax, out, n4v, n4c);

    int nchunk = (nnz + 15) / 16;
    scatter_kernel<<<(nchunk + BLK - 1) / BLK, BLK, 0, stream>>>(
        (const vfloat4*)coeff, (const vint4*)constr_idx, (const vint4*)var_idx,
        values, ax, nnz);

    violation_kernel<<<(n4c + BLK - 1) / BLK, BLK, 0, stream>>>(
        (const vfloat4*)ax, (const vfloat4*)rhs, (const vint4*)sense,
        out, n4c, 1.0f / (float)n_constrs);
}